// Round 3
// baseline (395.070 us; speedup 1.0000x reference)
//
#include <hip/hip_runtime.h>

// MakeCutouts: out[(n*B+b), c, i, j] = x[b, c, oy[n] + i*sz[n]/224, ox[n] + j*sz[n]/224]
// B=16, C=3, H=W=512, CUTN=32, CUT_SIZE=224. Output fp32, 308 MB.
//
// v3 = v2 (verified-correct LDS depth-3 pipeline) + XCD-aware task remap (T1).
// Round-0 (no-LDS gather, no waits) == round-2 (LDS pipeline) == ~195us kernel
// => bottleneck is the shared L2/L3 read path: 688 MB of row staging against a
// 48 MB input with blocks round-robined across 8 XCDs (4 MB L2 each) -> L2
// misses -> L3 at ~600cy. Remap so each XCD owns 6 whole images (6 MB): all
// 32n x 4chunk tasks of one (b,c) image land on one XCD -> staging hits L2.
//
// SYNC RULE (unchanged from v2, verified): vmcnt(N) with N = #loads issued
// AFTER the load group we need; stores in the counter can only cause over-wait.

#define CUT_SIZE 224
#define CUTN     32
#define BATCH    16
#define CHAN     3
#define HEIGHT   512
#define WIDTH    512
#define GROUPS   (CUTN * BATCH * CHAN)   // 1536 (n,b,c) groups
#define I_PER_WAVE 56
#define CHUNKS   (CUT_SIZE / I_PER_WAVE) // 4
#define WPB      4                        // waves per block
#define DEPTH    3                        // pipeline depth (rows in flight)
#define NXCD     8

typedef const __attribute__((address_space(1))) void* gas_ptr;
typedef __attribute__((address_space(3))) void*       las_ptr;

__device__ __forceinline__ void stage_row(const float* src_row, float* lds_buf, int lane)
{
    // Stage 2048 B (one full input row): 2 x (64 lanes x 16 B).
    // LDS dest is wave-uniform base + lane*16 (HW rule); global src is per-lane.
    __builtin_amdgcn_global_load_lds((gas_ptr)(src_row + lane * 4),
                                     (las_ptr)(lds_buf), 16, 0, 0);
    __builtin_amdgcn_global_load_lds((gas_ptr)(src_row + 256 + lane * 4),
                                     (las_ptr)(lds_buf + 256), 16, 0, 0);
}

__global__ __launch_bounds__(256) void make_cutouts_kernel(
    const float* __restrict__ x,
    const int*   __restrict__ sizes,
    const int*   __restrict__ offsetx,
    const int*   __restrict__ offsety,
    float*       __restrict__ out)
{
    __shared__ __align__(16) float lds[WPB][DEPTH][WIDTH];   // 24 KB/block -> 6 blocks/CU

    const int wid  = threadIdx.x >> 6;
    const int lane = threadIdx.x & 63;

    // XCD-aware remap (assumes dispatch round-robins blockIdx over 8 XCDs, m09):
    //   xcd = bid&7 owns images {xcd, xcd+8, ..., xcd+40} (6 images = 6 MB).
    //   Per image: 32 blocks (one per n), 4 waves = 4 chunks. Bijective:
    //   48 images x 32 n = 1536 blocks; (img,n,chunk) covers every task once.
    const int bid = blockIdx.x;
    const int xcd = bid & (NXCD - 1);
    const int s   = bid >> 3;            // 0..191
    const int img = xcd + NXCD * (s >> 5); // 0..47
    const int n   = s & 31;              // cutout index
    const int b   = img / CHAN;
    const int c   = img % CHAN;
    const int chunk = wid;               // 56-row slice

    const int g = (n * BATCH + b) * CHAN + c;   // output group index

    const int sz = sizes[n];
    const int ox = offsetx[n];
    const int oy = offsety[n];

    const float* img_p = x + (size_t)(b * CHAN + c) * (HEIGHT * WIDTH);
    float*       outg  = out + (size_t)g * (CUT_SIZE * CUT_SIZE)
                             + (size_t)(chunk * I_PER_WAVE) * CUT_SIZE;

    // Per-lane gather x-offsets: invariant across i (depend only on n, lane).
    const unsigned usz = (unsigned)sz;
    const int xi0 = ox + (int)(((unsigned)(lane      ) * usz) / CUT_SIZE);
    const int xi1 = ox + (int)(((unsigned)(lane +  64) * usz) / CUT_SIZE);
    const int xi2 = ox + (int)(((unsigned)(lane + 128) * usz) / CUT_SIZE);
    const int xi3 = (lane < 32)
                  ? ox + (int)(((unsigned)(lane + 192) * usz) / CUT_SIZE)
                  : xi0;   // clamped: value unused for lane>=32, keeps LDS read in-bounds

    float* p0 = &lds[wid][0][0];   // holds row k   (at iteration k)
    float* p1 = &lds[wid][1][0];   // holds row k+1
    float* p2 = &lds[wid][2][0];   // holds row k+2

    const int ibase = chunk * I_PER_WAVE;

    #define ROW_PTR(K) (img_p + (size_t)(oy + (int)(((unsigned)((ibase + (K)) * sz)) / CUT_SIZE)) * WIDTH)

    // Prologue: stage rows 0,1,2 (6 loads outstanding).
    stage_row(ROW_PTR(0), p0, lane);
    stage_row(ROW_PTR(1), p1, lane);
    stage_row(ROW_PTR(2), p2, lane);

    for (int k = 0; k < I_PER_WAVE; ++k) {
        // Before gather(k): loads newer than row k's = rows (k+1..min(k+2,55)),
        // i.e. 4 in steady state, 2 / 0 in the 2-iteration tail. Stores mixed
        // into vmcnt only add to the count -> over-wait (safe).
        if      (k <  I_PER_WAVE - 2) { asm volatile("s_waitcnt vmcnt(4)" ::: "memory"); }
        else if (k == I_PER_WAVE - 2) { asm volatile("s_waitcnt vmcnt(2)" ::: "memory"); }
        else                          { asm volatile("s_waitcnt vmcnt(0)" ::: "memory"); }
        __builtin_amdgcn_sched_barrier(0);

        const float v0 = p0[xi0];
        const float v1 = p0[xi1];
        const float v2 = p0[xi2];
        const float v3 = p0[xi3];

        // Drain the ds_reads (data safely in VGPRs) before the DMA restage
        // overwrites p0's buffer; sched_barrier pins the order (rule #18).
        asm volatile("s_waitcnt lgkmcnt(0)" ::: "memory");
        __builtin_amdgcn_sched_barrier(0);

        // Restage p0's buffer with row k+3. Issued BEFORE the stores so the
        // newest ops at the next wait are stores -> they stay in flight.
        if (k + DEPTH < I_PER_WAVE) {
            stage_row(ROW_PTR(k + DEPTH), p0, lane);
        }

        float* orow = outg + (size_t)k * CUT_SIZE;
        orow[lane      ] = v0;
        orow[lane +  64] = v1;
        orow[lane + 128] = v2;
        if (lane < 32) orow[lane + 192] = v3;

        // Rotate: p0<-row k+1, p1<-row k+2, p2<-row k+3 (just staged).
        float* t = p0; p0 = p1; p1 = p2; p2 = t;
    }
    #undef ROW_PTR
}

extern "C" void kernel_launch(void* const* d_in, const int* in_sizes, int n_in,
                              void* d_out, int out_size, void* d_ws, size_t ws_size,
                              hipStream_t stream) {
    const float* x       = (const float*)d_in[0];
    const int*   sizes   = (const int*)d_in[1];
    const int*   offsetx = (const int*)d_in[2];
    const int*   offsety = (const int*)d_in[3];
    float*       out     = (float*)d_out;

    const int grid = GROUPS * CHUNKS / WPB;   // 1536 blocks x 256 threads
    make_cutouts_kernel<<<grid, 256, 0, stream>>>(x, sizes, offsetx, offsety, out);
}

// Round 4
// 352.460 us; speedup vs baseline: 1.1209x; 1.1209x over previous
//
#include <hip/hip_runtime.h>

// MakeCutouts: out[(n*B+b), c, i, j] = x[b, c, oy[n] + i*sz[n]/224, ox[n] + j*sz[n]/224]
// B=16, C=3, H=W=512, CUTN=32, CUT_SIZE=224. Output fp32, 308 MB.
//
// v4: inverted loop nest to kill 14x read amplification (688 MB -> 48 MB).
// Previous variants fetched the full 2KB input row once PER OUTPUT ROW
// (6144 tasks x 56 rows x 2KB = 688 MB vs 48 MB input); L2 thrashed, L3
// served ~3.6 TB/s -> the ~190us kernel wall. Now: block = (image, 16-row
// input slice); stage slice to LDS ONCE, then emit every output row (n,i)
// whose source row lands in the slice. Each input byte is read exactly once.
//
// Inverse map (valid because sz >= 224 => i -> y strictly increasing):
//   rows of cutout n in slice [y0,y0+R): i in [ceil(224*(y0-oy)/sz),
//                                              ceil(224*(y0+R-oy)/sz)) ∩ [0,224)

#define CUT_SIZE 224
#define CUTN     32
#define BATCH    16
#define CHAN     3
#define HEIGHT   512
#define WIDTH    512
#define R_SLICE  16                      // input rows per block
#define NSLICE   (HEIGHT / R_SLICE)      // 32
#define NIMG     (BATCH * CHAN)          // 48
#define WPB      4                        // waves per block

typedef const __attribute__((address_space(1))) void* gas_ptr;
typedef __attribute__((address_space(3))) void*       las_ptr;

__device__ __forceinline__ void stage_row(const float* src_row, float* lds_buf, int lane)
{
    // Stage 2048 B (one full input row): 2 x (64 lanes x 16 B).
    // LDS dest is wave-uniform base + lane*16 (HW rule); global src is per-lane.
    __builtin_amdgcn_global_load_lds((gas_ptr)(src_row + lane * 4),
                                     (las_ptr)(lds_buf), 16, 0, 0);
    __builtin_amdgcn_global_load_lds((gas_ptr)(src_row + 256 + lane * 4),
                                     (las_ptr)(lds_buf + 256), 16, 0, 0);
}

__global__ __launch_bounds__(256) void make_cutouts_kernel(
    const float* __restrict__ x,
    const int*   __restrict__ sizes,
    const int*   __restrict__ offsetx,
    const int*   __restrict__ offsety,
    float*       __restrict__ out)
{
    __shared__ __align__(16) float lds[R_SLICE][WIDTH];   // 32 KB -> 5 blocks/CU

    const int wid  = threadIdx.x >> 6;
    const int lane = threadIdx.x & 63;

    const int bid   = blockIdx.x;        // 0..1535
    const int img   = bid >> 5;          // 0..47  (b,c)
    const int slice = bid & (NSLICE - 1);// 0..31
    const int b     = img / CHAN;
    const int c     = img % CHAN;
    const int y0    = slice * R_SLICE;

    const float* img_p = x + (size_t)img * (HEIGHT * WIDTH);

    // --- Stage the 16-row slice once: wave wid stages rows wid*4 .. wid*4+3.
    #pragma unroll
    for (int r = 0; r < R_SLICE / WPB; ++r) {
        const int row = wid * (R_SLICE / WPB) + r;
        stage_row(img_p + (size_t)(y0 + row) * WIDTH, &lds[row][0], lane);
    }
    asm volatile("s_waitcnt vmcnt(0)" ::: "memory");
    __syncthreads();

    // --- Compute: wave wid serves cutouts n = wid, wid+4, ..., wid+28.
    for (int nn = 0; nn < CUTN / WPB; ++nn) {
        const int n  = wid + nn * WPB;
        const int sz = sizes[n];
        const int ox = offsetx[n];
        const int oy = offsety[n];

        // i-range of output rows sourced from this slice.
        const int d0 = y0 - oy;
        const int d1 = y0 + R_SLICE - oy;
        int i0 = (d0 <= 0) ? 0 : (int)(((unsigned)(d0 * CUT_SIZE) + (unsigned)sz - 1u) / (unsigned)sz);
        int i1 = (d1 <= 0) ? 0 : (int)(((unsigned)(d1 * CUT_SIZE) + (unsigned)sz - 1u) / (unsigned)sz);
        if (i1 > CUT_SIZE) i1 = CUT_SIZE;
        if (i0 >= i1) continue;

        // Per-lane gather x-offsets (invariant over i).
        const unsigned usz = (unsigned)sz;
        const int xi0 = ox + (int)(((unsigned)(lane      ) * usz) / CUT_SIZE);
        const int xi1 = ox + (int)(((unsigned)(lane +  64) * usz) / CUT_SIZE);
        const int xi2 = ox + (int)(((unsigned)(lane + 128) * usz) / CUT_SIZE);
        const int xi3 = (lane < 32)
                      ? ox + (int)(((unsigned)(lane + 192) * usz) / CUT_SIZE)
                      : xi0;   // clamped: unused for lane>=32, keeps LDS read in-bounds

        float* og = out + (size_t)((n * BATCH + b) * CHAN + c) * (CUT_SIZE * CUT_SIZE);

        for (int i = i0; i < i1; ++i) {
            const int y = oy + (int)(((unsigned)(i * (int)usz)) / CUT_SIZE);
            const float* lrow = &lds[y - y0][0];

            const float v0 = lrow[xi0];
            const float v1 = lrow[xi1];
            const float v2 = lrow[xi2];
            const float v3 = lrow[xi3];

            float* orow = og + (size_t)i * CUT_SIZE;
            orow[lane      ] = v0;
            orow[lane +  64] = v1;
            orow[lane + 128] = v2;
            if (lane < 32) orow[lane + 192] = v3;
        }
    }
}

extern "C" void kernel_launch(void* const* d_in, const int* in_sizes, int n_in,
                              void* d_out, int out_size, void* d_ws, size_t ws_size,
                              hipStream_t stream) {
    const float* x       = (const float*)d_in[0];
    const int*   sizes   = (const int*)d_in[1];
    const int*   offsetx = (const int*)d_in[2];
    const int*   offsety = (const int*)d_in[3];
    float*       out     = (float*)d_out;

    const int grid = NIMG * NSLICE;   // 1536 blocks x 256 threads
    make_cutouts_kernel<<<grid, 256, 0, stream>>>(x, sizes, offsetx, offsety, out);
}